// Round 7
// baseline (100.288 us; speedup 1.0000x reference)
//
#include <hip/hip_runtime.h>

// Gaussian-kernel MMD loss, N=M=8192, D=2 — 3 plain launches:
//   prep (means/constants) -> main (1056 static 512x256 tiles) -> final.
// loss = mean(k_bb) + mean(k_tt) - 2*mean(k_bt), k = exp(-||x-y||^2/(2 s^2))
// - Centering affects only the cross term: shift folded into A (base) side.
// - Coords pre-scaled by exp(log_scale)*sqrt(inv2s2*log2e); dot-form exponent
//   e = 2ax*bx + 2ay*by - |a|^2 - |b|^2; k = exp2(e).
// - Tiles 512 rows x 256 cols, 4 rows per thread (amortizes the 3 LDS b128
//   reads per col-quad over 16 pairs/lane; 16 independent exp2 chains).
//   Cross: 16x32 = 512 tiles. Sym per term: (r,c) with c >= 2r -> 272 tiles;
//   c in {2r, 2r+1} is the diagonal band -> per-pair mask (2/1/0 weights).
// - SoA LDS (bx, by, c) + float2 ext-vector math -> v_pk_fma_f32.
// - Block partials -> 64 spread f64 atomic slots; tiny final kernel reduces.

#define BLOCK 256
#define NT_CROSS 512
#define NT_TOT   1056
#define LOG2E 1.4426950408889634f

typedef float v2f __attribute__((ext_vector_type(2)));

struct Prep { float f0, f1, sh0, sh1; };

__device__ __forceinline__ float fexp2(float x) {
    return __builtin_amdgcn_exp2f(x);
}

// ---------------- prep: means, constants, zero slots ----------------
__global__ __launch_bounds__(1024) void prep_kernel(
    const float* __restrict__ base, const float* __restrict__ target,
    const float* __restrict__ log_sigma, const float* __restrict__ log_scale,
    int N, int M, Prep* __restrict__ pp, double* __restrict__ slots)
{
    __shared__ double mred[16][4];
    const int tid = threadIdx.x;
    if (tid < 64) slots[tid] = 0.0;

    double sbx = 0, sby = 0, stx = 0, sty = 0;
    const float4* b4 = (const float4*)base;
    const float4* t4 = (const float4*)target;
    for (int i = tid; i < (N >> 1); i += 1024) {
        float4 v = b4[i];
        sbx += (double)v.x + (double)v.z;
        sby += (double)v.y + (double)v.w;
    }
    for (int i = tid; i < (M >> 1); i += 1024) {
        float4 v = t4[i];
        stx += (double)v.x + (double)v.z;
        sty += (double)v.y + (double)v.w;
    }
    for (int off = 32; off; off >>= 1) {
        sbx += __shfl_down(sbx, off); sby += __shfl_down(sby, off);
        stx += __shfl_down(stx, off); sty += __shfl_down(sty, off);
    }
    if ((tid & 63) == 0) {
        mred[tid >> 6][0] = sbx; mred[tid >> 6][1] = sby;
        mred[tid >> 6][2] = stx; mred[tid >> 6][3] = sty;
    }
    __syncthreads();
    if (tid == 0) {
        double b0 = 0, b1 = 0, t0 = 0, t1 = 0;
        for (int k = 0; k < 16; ++k) {
            b0 += mred[k][0]; b1 += mred[k][1];
            t0 += mred[k][2]; t1 += mred[k][3];
        }
        float s0 = expf(log_scale[0]);
        float s1 = expf(log_scale[1]);
        float sigma = expf(log_sigma[0]);
        float inv2s2 = 1.0f / (2.0f * sigma * sigma);
        float sq = sqrtf(inv2s2 * LOG2E);
        float f0 = s0 * sq, f1 = s1 * sq;
        pp->f0 = f0; pp->f1 = f1;
        pp->sh0 = (float)(b0 / (double)N - t0 / (double)M) * f0;
        pp->sh1 = (float)(b1 / (double)N - t1 / (double)M) * f1;
    }
}

// ---------------- main: 1056 static 512x256 tiles, 4 rows/thread ----------
__global__ __launch_bounds__(BLOCK, 4) void mmd_main(
    const float* __restrict__ base, const float* __restrict__ target,
    int N, int M, const Prep* __restrict__ pp, double* __restrict__ slots)
{
    __shared__ __align__(16) float tbx[256];
    __shared__ __align__(16) float tby[256];
    __shared__ __align__(16) float tbc[256];
    __shared__ double wredd[4];

    const int tid = threadIdx.x;
    const int t   = blockIdx.x;
    const Prep p = *pp;
    const float2* base2   = (const float2*)base;
    const float2* target2 = (const float2*)target;

    const double wNN = 1.0 / ((double)N * (double)N);
    const double wMM = 1.0 / ((double)M * (double)M);
    const double wNM = -2.0 / ((double)N * (double)M);

    // ---- decode tile ----
    int ib, jb, term;
    bool diag;
    const float2* A2;
    const float2* B2;
    double wt;
    float shx = 0.f, shy = 0.f;
    if (t < NT_CROSS) {
        ib = t >> 5; jb = t & 31;
        A2 = base2; B2 = target2;
        wt = wNM; diag = false; term = 2;
        shx = p.sh0; shy = p.sh1;
    } else {
        const int u = t - NT_CROSS;
        term = (u >= 272) ? 1 : 0;
        const int v = u - term * 272;
        // largest r with cum(r) = r*(33-r) <= v, r in [0,15]
        int r = (int)((33.0f - sqrtf(1089.0f - 4.0f * (float)v)) * 0.5f);
        r = min(max(r, 0), 15);
        while (r > 0 && r * (33 - r) > v) --r;
        while (r < 15 && (r + 1) * (32 - r) <= v) ++r;
        ib = r;
        jb = 2 * r + (v - r * (33 - r));
        diag = (jb <= 2 * r + 1);
        A2 = term ? target2 : base2;  B2 = A2;
        wt = 2.0 * (term ? wMM : wNN);
    }
    const int i0 = ib * 512, j0 = jb * 256;

    // ---- stage B columns (SoA, scaled) ----
    {
        float2 b = B2[j0 + tid];
        float bx = b.x * p.f0, by = b.y * p.f1;
        tbx[tid] = bx;
        tby[tid] = by;
        tbc[tid] = -fmaf(bx, bx, by * by);
    }
    __syncthreads();

    // ---- per-thread rows: i0 + (tid&127) + 128k, k = 0..3 ----
    const int r0  = i0 + (tid & 127);
    const int js  = (tid >> 7) * 128;

    float ax2s[4], ay2s[4], A0s[4];
#pragma unroll
    for (int k = 0; k < 4; ++k) {
        float2 a = A2[r0 + 128 * k];
        float ax = fmaf(a.x, p.f0, -shx);
        float ay = fmaf(a.y, p.f1, -shy);
        ax2s[k] = ax + ax;
        ay2s[k] = ay + ay;
        A0s[k]  = -fmaf(ax, ax, ay * ay);
    }

    const float4* bx4 = (const float4*)(tbx + js);
    const float4* by4 = (const float4*)(tby + js);
    const float4* c4  = (const float4*)(tbc + js);

    double result;
    if (!diag) {
        v2f s[4][2];
#pragma unroll
        for (int k = 0; k < 4; ++k) { s[k][0] = (v2f){0.f, 0.f}; s[k][1] = (v2f){0.f, 0.f}; }
#pragma unroll 4
        for (int q = 0; q < 32; ++q) {
            float4 BX = bx4[q];
            float4 BY = by4[q];
            float4 C  = c4[q];
            v2f bx01 = { BX.x, BX.y }, bx23 = { BX.z, BX.w };
            v2f by01 = { BY.x, BY.y }, by23 = { BY.z, BY.w };
            v2f c01  = { C.x,  C.y  }, c23  = { C.z,  C.w  };
#pragma unroll
            for (int k = 0; k < 4; ++k) {
                v2f A0v  = { A0s[k],  A0s[k]  };
                v2f ax2v = { ax2s[k], ax2s[k] };
                v2f ay2v = { ay2s[k], ay2s[k] };
                v2f e01 = ax2v * bx01 + (ay2v * by01 + (c01 + A0v));
                v2f e23 = ax2v * bx23 + (ay2v * by23 + (c23 + A0v));
                s[k][0] += (v2f){ fexp2(e01.x), fexp2(e01.y) };
                s[k][1] += (v2f){ fexp2(e23.x), fexp2(e23.y) };
            }
        }
        double tot = 0.0;
#pragma unroll
        for (int k = 0; k < 4; ++k) {
            v2f st = s[k][0] + s[k][1];
            tot += (double)(st.x + st.y);
        }
        result = wt * tot;
    } else {
        // weight 2 for col>row, 1 for col==row, 0 for col<row  (= sge + sgt)
        float sge = 0.f, sgt = 0.f;
        const int jbase = j0 + js;
#pragma unroll 2
        for (int q = 0; q < 32; ++q) {
            float4 BX = bx4[q];
            float4 BY = by4[q];
            float4 C  = c4[q];
            const int j = jbase + 4 * q;
#pragma unroll
            for (int k = 0; k < 4; ++k) {
                const int row = r0 + 128 * k;
                float e0 = fmaf(ax2s[k], BX.x, fmaf(ay2s[k], BY.x, C.x + A0s[k]));
                float e1 = fmaf(ax2s[k], BX.y, fmaf(ay2s[k], BY.y, C.y + A0s[k]));
                float e2 = fmaf(ax2s[k], BX.z, fmaf(ay2s[k], BY.z, C.z + A0s[k]));
                float e3 = fmaf(ax2s[k], BX.w, fmaf(ay2s[k], BY.w, C.w + A0s[k]));
                float v0 = fexp2(e0), v1 = fexp2(e1);
                float v2 = fexp2(e2), v3 = fexp2(e3);
                sge += (j + 0 >= row) ? v0 : 0.f;  sgt += (j + 0 > row) ? v0 : 0.f;
                sge += (j + 1 >= row) ? v1 : 0.f;  sgt += (j + 1 > row) ? v1 : 0.f;
                sge += (j + 2 >= row) ? v2 : 0.f;  sgt += (j + 2 > row) ? v2 : 0.f;
                sge += (j + 3 >= row) ? v3 : 0.f;  sgt += (j + 3 > row) ? v3 : 0.f;
            }
        }
        result = (term ? wMM : wNN) * (double)(sge + sgt);
    }

    // ---- block reduce (f64), publish to spread slots ----
    for (int off = 32; off; off >>= 1) result += __shfl_down(result, off);
    if ((tid & 63) == 0) wredd[tid >> 6] = result;
    __syncthreads();
    if (tid == 0) {
        double s = wredd[0] + wredd[1] + wredd[2] + wredd[3];
        atomicAdd(&slots[t & 63], s);
    }
}

// ---------------- final: reduce 64 slots ----------------
__global__ void final_kernel(const double* __restrict__ slots,
                             float* __restrict__ out)
{
    const int tid = threadIdx.x;
    double s = slots[tid];
    for (int off = 32; off; off >>= 1) s += __shfl_down(s, off);
    if (tid == 0) out[0] = (float)s;
}

extern "C" void kernel_launch(void* const* d_in, const int* in_sizes, int n_in,
                              void* d_out, int out_size, void* d_ws, size_t ws_size,
                              hipStream_t stream)
{
    const float* base      = (const float*)d_in[0];
    const float* target    = (const float*)d_in[1];
    const float* log_sigma = (const float*)d_in[2];
    const float* log_scale = (const float*)d_in[3];
    float* out = (float*)d_out;

    int N = in_sizes[0] / 2;
    int M = in_sizes[1] / 2;

    Prep*   pp    = (Prep*)d_ws;                       // 16 B
    double* slots = (double*)((char*)d_ws + 64);       // 64 doubles

    prep_kernel<<<1, 1024, 0, stream>>>(base, target, log_sigma, log_scale,
                                        N, M, pp, slots);
    mmd_main<<<NT_TOT, BLOCK, 0, stream>>>(base, target, N, M, pp, slots);
    final_kernel<<<1, 64, 0, stream>>>(slots, out);
}

// Round 8
// 90.533 us; speedup vs baseline: 1.1078x; 1.1078x over previous
//
#include <hip/hip_runtime.h>

// Gaussian-kernel MMD loss, N=M=8192, D=2 — 3 plain launches:
//   prep (means/constants) -> main (2080 static 256x256 tiles) -> final.
// loss = mean(k_bb) + mean(k_tt) - 2*mean(k_bt), k = exp(-||x-y||^2/(2 s^2))
// - Centering affects only the cross term: shift folded into A (base) side.
// - Coords pre-scaled by exp(log_scale)*sqrt(inv2s2*log2e); dot-form exponent
//   e = 2ax*bx + 2ay*by - |a|^2 - |b|^2; k = exp2(e).
// - Tiles 256 rows x 256 cols, 2 rows/thread (tid&127, +128), half-wave col
//   split (js = (tid>>7)*128): 3 ds_read_b128 per col-quad serve 8 pairs.
//   2 rows (not 4): keeps VGPR ~45 < 64 cap of (256,8) — R7's 4-row variant
//   spilled under the 128-VGPR cap and regressed.
// - Cross: 32x32 = 1024 tiles. Sym per term: upper triangle 528 tiles
//   (off-diag weight 2, diagonal tiles per-pair masked 2/1/0).
// - SoA LDS (bx, by, c) + float2 ext-vector math -> v_pk_fma_f32.
// - Block partials -> 64 spread f64 atomic slots; tiny final kernel reduces.

#define BLOCK 256
#define NT_CROSS 1024
#define NT_TOT   2080
#define LOG2E 1.4426950408889634f

typedef float v2f __attribute__((ext_vector_type(2)));

struct Prep { float f0, f1, sh0, sh1; };

__device__ __forceinline__ float fexp2(float x) {
    return __builtin_amdgcn_exp2f(x);
}

// ---------------- prep: means, constants, zero slots ----------------
__global__ __launch_bounds__(1024) void prep_kernel(
    const float* __restrict__ base, const float* __restrict__ target,
    const float* __restrict__ log_sigma, const float* __restrict__ log_scale,
    int N, int M, Prep* __restrict__ pp, double* __restrict__ slots)
{
    __shared__ double mred[16][4];
    const int tid = threadIdx.x;
    if (tid < 64) slots[tid] = 0.0;

    double sbx = 0, sby = 0, stx = 0, sty = 0;
    const float4* b4 = (const float4*)base;
    const float4* t4 = (const float4*)target;
    for (int i = tid; i < (N >> 1); i += 1024) {
        float4 v = b4[i];
        sbx += (double)v.x + (double)v.z;
        sby += (double)v.y + (double)v.w;
    }
    for (int i = tid; i < (M >> 1); i += 1024) {
        float4 v = t4[i];
        stx += (double)v.x + (double)v.z;
        sty += (double)v.y + (double)v.w;
    }
    for (int off = 32; off; off >>= 1) {
        sbx += __shfl_down(sbx, off); sby += __shfl_down(sby, off);
        stx += __shfl_down(stx, off); sty += __shfl_down(sty, off);
    }
    if ((tid & 63) == 0) {
        mred[tid >> 6][0] = sbx; mred[tid >> 6][1] = sby;
        mred[tid >> 6][2] = stx; mred[tid >> 6][3] = sty;
    }
    __syncthreads();
    if (tid == 0) {
        double b0 = 0, b1 = 0, t0 = 0, t1 = 0;
        for (int k = 0; k < 16; ++k) {
            b0 += mred[k][0]; b1 += mred[k][1];
            t0 += mred[k][2]; t1 += mred[k][3];
        }
        float s0 = expf(log_scale[0]);
        float s1 = expf(log_scale[1]);
        float sigma = expf(log_sigma[0]);
        float inv2s2 = 1.0f / (2.0f * sigma * sigma);
        float sq = sqrtf(inv2s2 * LOG2E);
        float f0 = s0 * sq, f1 = s1 * sq;
        pp->f0 = f0; pp->f1 = f1;
        pp->sh0 = (float)(b0 / (double)N - t0 / (double)M) * f0;
        pp->sh1 = (float)(b1 / (double)N - t1 / (double)M) * f1;
    }
}

// ---------------- main: 2080 static 256x256 tiles, 2 rows/thread ----------
__global__ __launch_bounds__(BLOCK, 8) void mmd_main(
    const float* __restrict__ base, const float* __restrict__ target,
    int N, int M, const Prep* __restrict__ pp, double* __restrict__ slots)
{
    __shared__ __align__(16) float tbx[256];
    __shared__ __align__(16) float tby[256];
    __shared__ __align__(16) float tbc[256];
    __shared__ double wredd[4];

    const int tid = threadIdx.x;
    const int t   = blockIdx.x;
    const Prep p = *pp;
    const float2* base2   = (const float2*)base;
    const float2* target2 = (const float2*)target;

    const double wNN = 1.0 / ((double)N * (double)N);
    const double wMM = 1.0 / ((double)M * (double)M);
    const double wNM = -2.0 / ((double)N * (double)M);

    // ---- decode tile ----
    int ib, jb, term;
    bool diag;
    const float2* A2;
    const float2* B2;
    double wt;
    float shx = 0.f, shy = 0.f;
    if (t < NT_CROSS) {
        ib = t >> 5; jb = t & 31;
        A2 = base2; B2 = target2;
        wt = wNM; diag = false; term = 2;
        shx = p.sh0; shy = p.sh1;
    } else {
        const int u = t - NT_CROSS;
        term = (u >= 528) ? 1 : 0;
        const int v = u - term * 528;
        // largest r with cum(r) = r*(65-r)/2 <= v, r in [0,31]  (R4-verified)
        int r = (int)((65.0f - sqrtf(4225.0f - 8.0f * (float)v)) * 0.5f);
        r = min(max(r, 0), 31);
        while (r > 0 && (r * (65 - r)) / 2 > v) --r;
        while (r < 31 && ((r + 1) * (64 - r)) / 2 <= v) ++r;
        ib = r;
        jb = r + (v - (r * (65 - r)) / 2);
        diag = (jb == ib);
        A2 = term ? target2 : base2;  B2 = A2;
        wt = 2.0 * (term ? wMM : wNN);
    }
    const int i0 = ib * 256, j0 = jb * 256;

    // ---- stage B columns (SoA, scaled) ----
    {
        float2 b = B2[j0 + tid];
        float bx = b.x * p.f0, by = b.y * p.f1;
        tbx[tid] = bx;
        tby[tid] = by;
        tbc[tid] = -fmaf(bx, bx, by * by);
    }
    __syncthreads();

    // ---- per-thread rows: r0 = i0 + (tid&127), r1 = r0 + 128 ----
    const int r0 = i0 + (tid & 127);
    const int js = (tid >> 7) * 128;

    float ax2s[2], ay2s[2], A0s[2];
#pragma unroll
    for (int k = 0; k < 2; ++k) {
        float2 a = A2[r0 + 128 * k];
        float ax = fmaf(a.x, p.f0, -shx);
        float ay = fmaf(a.y, p.f1, -shy);
        ax2s[k] = ax + ax;
        ay2s[k] = ay + ay;
        A0s[k]  = -fmaf(ax, ax, ay * ay);
    }

    const float4* bx4 = (const float4*)(tbx + js);
    const float4* by4 = (const float4*)(tby + js);
    const float4* c4  = (const float4*)(tbc + js);

    double result;
    if (!diag) {
        v2f s00 = {0.f, 0.f}, s01 = {0.f, 0.f};
        v2f s10 = {0.f, 0.f}, s11 = {0.f, 0.f};
#pragma unroll 4
        for (int q = 0; q < 32; ++q) {
            float4 BX = bx4[q];
            float4 BY = by4[q];
            float4 C  = c4[q];
            v2f bxa = { BX.x, BX.y }, bxb = { BX.z, BX.w };
            v2f bya = { BY.x, BY.y }, byb = { BY.z, BY.w };
            v2f ca  = { C.x,  C.y  }, cb  = { C.z,  C.w  };
            {
                v2f A0v = { A0s[0], A0s[0] };
                v2f axv = { ax2s[0], ax2s[0] };
                v2f ayv = { ay2s[0], ay2s[0] };
                v2f ea = axv * bxa + (ayv * bya + (ca + A0v));
                v2f eb = axv * bxb + (ayv * byb + (cb + A0v));
                s00 += (v2f){ fexp2(ea.x), fexp2(ea.y) };
                s01 += (v2f){ fexp2(eb.x), fexp2(eb.y) };
            }
            {
                v2f A0v = { A0s[1], A0s[1] };
                v2f axv = { ax2s[1], ax2s[1] };
                v2f ayv = { ay2s[1], ay2s[1] };
                v2f ea = axv * bxa + (ayv * bya + (ca + A0v));
                v2f eb = axv * bxb + (ayv * byb + (cb + A0v));
                s10 += (v2f){ fexp2(ea.x), fexp2(ea.y) };
                s11 += (v2f){ fexp2(eb.x), fexp2(eb.y) };
            }
        }
        v2f st0 = s00 + s01;
        v2f st1 = s10 + s11;
        result = wt * ((double)(st0.x + st0.y) + (double)(st1.x + st1.y));
    } else {
        // weight 2 for col>row, 1 for col==row, 0 for col<row  (= sge + sgt)
        float sge = 0.f, sgt = 0.f;
        const int jbase = j0 + js;
#pragma unroll 2
        for (int q = 0; q < 32; ++q) {
            float4 BX = bx4[q];
            float4 BY = by4[q];
            float4 C  = c4[q];
            const int j = jbase + 4 * q;
#pragma unroll
            for (int k = 0; k < 2; ++k) {
                const int row = r0 + 128 * k;
                float e0 = fmaf(ax2s[k], BX.x, fmaf(ay2s[k], BY.x, C.x + A0s[k]));
                float e1 = fmaf(ax2s[k], BX.y, fmaf(ay2s[k], BY.y, C.y + A0s[k]));
                float e2 = fmaf(ax2s[k], BX.z, fmaf(ay2s[k], BY.z, C.z + A0s[k]));
                float e3 = fmaf(ax2s[k], BX.w, fmaf(ay2s[k], BY.w, C.w + A0s[k]));
                float v0 = fexp2(e0), v1 = fexp2(e1);
                float v2 = fexp2(e2), v3 = fexp2(e3);
                sge += (j + 0 >= row) ? v0 : 0.f;  sgt += (j + 0 > row) ? v0 : 0.f;
                sge += (j + 1 >= row) ? v1 : 0.f;  sgt += (j + 1 > row) ? v1 : 0.f;
                sge += (j + 2 >= row) ? v2 : 0.f;  sgt += (j + 2 > row) ? v2 : 0.f;
                sge += (j + 3 >= row) ? v3 : 0.f;  sgt += (j + 3 > row) ? v3 : 0.f;
            }
        }
        result = (term ? wMM : wNN) * (double)(sge + sgt);
    }

    // ---- block reduce (f64), publish to spread slots ----
    for (int off = 32; off; off >>= 1) result += __shfl_down(result, off);
    if ((tid & 63) == 0) wredd[tid >> 6] = result;
    __syncthreads();
    if (tid == 0) {
        double s = wredd[0] + wredd[1] + wredd[2] + wredd[3];
        atomicAdd(&slots[t & 63], s);
    }
}

// ---------------- final: reduce 64 slots ----------------
__global__ void final_kernel(const double* __restrict__ slots,
                             float* __restrict__ out)
{
    const int tid = threadIdx.x;
    double s = slots[tid];
    for (int off = 32; off; off >>= 1) s += __shfl_down(s, off);
    if (tid == 0) out[0] = (float)s;
}

extern "C" void kernel_launch(void* const* d_in, const int* in_sizes, int n_in,
                              void* d_out, int out_size, void* d_ws, size_t ws_size,
                              hipStream_t stream)
{
    const float* base      = (const float*)d_in[0];
    const float* target    = (const float*)d_in[1];
    const float* log_sigma = (const float*)d_in[2];
    const float* log_scale = (const float*)d_in[3];
    float* out = (float*)d_out;

    int N = in_sizes[0] / 2;
    int M = in_sizes[1] / 2;

    Prep*   pp    = (Prep*)d_ws;                       // 16 B
    double* slots = (double*)((char*)d_ws + 64);       // 64 doubles

    prep_kernel<<<1, 1024, 0, stream>>>(base, target, log_sigma, log_scale,
                                        N, M, pp, slots);
    mmd_main<<<NT_TOT, BLOCK, 0, stream>>>(base, target, N, M, pp, slots);
    final_kernel<<<1, 64, 0, stream>>>(slots, out);
}